// Round 1
// baseline (95785.089 us; speedup 1.0000x reference)
//
#include <hip/hip_runtime.h>
#include <hip/hip_cooperative_groups.h>
#include <math.h>

namespace cg = cooperative_groups;

#define S_LEN 512
#define BATCH 64
#define IN_DIM 512
#define HID 512
#define DEPTH 5
#define N3 1536  // 3*HID

// =====================================================================
// Input projection GEMM:
//   HTC[m, n] = sum_k (h_mask[m&63, k] * inp[m, k]) * W3[n, k] + b3[n]
//   M = S*B = 32768, N = 1536 (H|T|C), K = 512
// =====================================================================
__global__ __launch_bounds__(256) void rhn_inproj(
    const float* __restrict__ inp, const float* __restrict__ h_mask,
    const float* __restrict__ Wih, const float* __restrict__ Wit,
    const float* __restrict__ Wic, const float* __restrict__ bih,
    const float* __restrict__ bit_, const float* __restrict__ bic,
    float* __restrict__ HTC)
{
    constexpr int BM = 64, BN = 64, BK = 16;
    __shared__ float As[BK][BM + 4];
    __shared__ float Bs[BK][BN + 4];
    const int m0 = blockIdx.x * BM;
    const int n0 = blockIdx.y * BN;
    const int tid = threadIdx.x;
    const int lr = tid >> 2;        // 0..63: row within tile for loads
    const int lk = (tid & 3) * 4;   // 0,4,8,12: k-offset for float4 load
    const int tx = tid & 15, ty = tid >> 4;

    const int n = n0 + lr;
    const float* Wrow = (n < 512) ? (Wih + (size_t)n * 512)
                       : (n < 1024) ? (Wit + (size_t)(n - 512) * 512)
                                    : (Wic + (size_t)(n - 1024) * 512);
    const int m = m0 + lr;
    const float* Arow = inp + (size_t)m * 512;
    const float* Mrow = h_mask + (size_t)(m & 63) * 512;

    float acc[4][4] = {};

    for (int k0 = 0; k0 < 512; k0 += BK) {
        float4 av = *(const float4*)(Arow + k0 + lk);
        float4 mv = *(const float4*)(Mrow + k0 + lk);
        float4 bv = *(const float4*)(Wrow + k0 + lk);
        As[lk + 0][lr] = av.x * mv.x;
        As[lk + 1][lr] = av.y * mv.y;
        As[lk + 2][lr] = av.z * mv.z;
        As[lk + 3][lr] = av.w * mv.w;
        Bs[lk + 0][lr] = bv.x;
        Bs[lk + 1][lr] = bv.y;
        Bs[lk + 2][lr] = bv.z;
        Bs[lk + 3][lr] = bv.w;
        __syncthreads();
#pragma unroll
        for (int kk = 0; kk < BK; ++kk) {
            float4 a = *(const float4*)&As[kk][ty * 4];
            float4 b = *(const float4*)&Bs[kk][tx * 4];
            acc[0][0] += a.x * b.x; acc[0][1] += a.x * b.y; acc[0][2] += a.x * b.z; acc[0][3] += a.x * b.w;
            acc[1][0] += a.y * b.x; acc[1][1] += a.y * b.y; acc[1][2] += a.y * b.z; acc[1][3] += a.y * b.w;
            acc[2][0] += a.z * b.x; acc[2][1] += a.z * b.y; acc[2][2] += a.z * b.z; acc[2][3] += a.z * b.w;
            acc[3][0] += a.w * b.x; acc[3][1] += a.w * b.y; acc[3][2] += a.w * b.z; acc[3][3] += a.w * b.w;
        }
        __syncthreads();
    }

    float bias[4];
#pragma unroll
    for (int j = 0; j < 4; ++j) {
        int nn = n0 + tx * 4 + j;
        bias[j] = (nn < 512) ? bih[nn] : (nn < 1024) ? bit_[nn - 512] : bic[nn - 1024];
    }
#pragma unroll
    for (int i = 0; i < 4; ++i) {
        int mm = m0 + ty * 4 + i;
        float4 o;
        o.x = acc[i][0] + bias[0];
        o.y = acc[i][1] + bias[1];
        o.z = acc[i][2] + bias[2];
        o.w = acc[i][3] + bias[3];
        *(float4*)(HTC + (size_t)mm * N3 + n0 + tx * 4) = o;
    }
}

// =====================================================================
// Recurrence: persistent cooperative kernel.
// 256 blocks x 256 threads. Block = (h-tile of 16) x (b-tile of 8).
// blockIdx = bi*32 + hi so all b-tiles of one h-tile share an XCD
// (round-robin %8 heuristic) -> weight rows stay L2-resident.
// Thread role: g = gate (0: Wh, 1: Wt), hl2 = h-group of 4, iq = i-quarter,
// bl = batch lane. Each thread dots 4 W-rows x 128 i; shuffle-reduce over iq.
// One grid.sync() per (step, layer) round: 2560 total.
// =====================================================================
__global__ __launch_bounds__(256) void rhn_scan(
    const float* __restrict__ s_h_mask,
    const float* __restrict__ Wh, const float* __restrict__ bh,
    const float* __restrict__ Wt, const float* __restrict__ bt,
    const float* __restrict__ HTC,
    float* __restrict__ s_buf,   // [2][64][512]
    float* __restrict__ out)     // outs [512][64][512] then last [64][512]
{
    constexpr int PAD = 4, LW = HID + PAD;  // 516: breaks row-stride bank alias
    __shared__ float mask_s[8][LW];
    __shared__ float sm_s[8][LW];
    __shared__ float linT[8][16];

    const int tid = threadIdx.x;
    const int hi = blockIdx.x & 31;
    const int bi = blockIdx.x >> 5;
    const int h0 = hi * 16, b0 = bi * 8;
    const int g   = tid >> 7;
    const int r   = tid & 127;
    const int hl2 = r >> 5;        // 0..3
    const int iq  = (r >> 3) & 3;  // 0..3 (lane bits 3-4: intra-wave)
    const int bl  = r & 7;
    const int hbase = h0 + hl2 * 4;

    // persistent dropout mask in LDS (same thread->slot mapping as staging)
    for (int p = tid; p < 1024; p += 256) {
        int b = p >> 7, i4 = p & 127;
        *(float4*)&mask_s[b][i4 * 4] =
            ((const float4*)(s_h_mask + (size_t)(b0 + b) * HID))[i4];
    }

    cg::grid_group grid = cg::this_grid();
    const float* Wg = g ? Wt : Wh;
    const float* bg = g ? bt : bh;

    int cur = 0;
    for (int step = 0; step < S_LEN; ++step) {
        for (int l = 0; l < DEPTH; ++l) {
            const float* sb_in = s_buf + cur * (BATCH * HID);
            // stage masked state sm = s_h_mask * s into LDS
            for (int p = tid; p < 1024; p += 256) {
                int b = p >> 7, i4 = p & 127;
                float4 v = ((const float4*)(sb_in + (size_t)(b0 + b) * HID))[i4];
                float4 m = *(const float4*)&mask_s[b][i4 * 4];
                v.x *= m.x; v.y *= m.y; v.z *= m.z; v.w *= m.w;
                *(float4*)&sm_s[b][i4 * 4] = v;
            }
            __syncthreads();

            const float* W0 = Wg + ((size_t)l * HID + hbase) * HID;
            const float* W1 = W0 + HID;
            const float* W2 = W0 + 2 * HID;
            const float* W3 = W0 + 3 * HID;
            float4 a0 = {0,0,0,0}, a1 = {0,0,0,0}, a2 = {0,0,0,0}, a3 = {0,0,0,0};
            const float4* smq = (const float4*)&sm_s[bl][0];
#pragma unroll 4
            for (int kk = 0; kk < 32; ++kk) {
                int i4 = iq * 32 + kk;
                float4 sv = smq[i4];
                float4 w0 = ((const float4*)W0)[i4];
                float4 w1 = ((const float4*)W1)[i4];
                float4 w2 = ((const float4*)W2)[i4];
                float4 w3 = ((const float4*)W3)[i4];
                a0.x += w0.x * sv.x; a0.y += w0.y * sv.y; a0.z += w0.z * sv.z; a0.w += w0.w * sv.w;
                a1.x += w1.x * sv.x; a1.y += w1.y * sv.y; a1.z += w1.z * sv.z; a1.w += w1.w * sv.w;
                a2.x += w2.x * sv.x; a2.y += w2.y * sv.y; a2.z += w2.z * sv.z; a2.w += w2.w * sv.w;
                a3.x += w3.x * sv.x; a3.y += w3.y * sv.y; a3.z += w3.z * sv.z; a3.w += w3.w * sv.w;
            }
            float lin[4];
            lin[0] = a0.x + a0.y + a0.z + a0.w;
            lin[1] = a1.x + a1.y + a1.z + a1.w;
            lin[2] = a2.x + a2.y + a2.z + a2.w;
            lin[3] = a3.x + a3.y + a3.z + a3.w;
#pragma unroll
            for (int j = 0; j < 4; ++j) {
                lin[j] += __shfl_xor(lin[j], 8);
                lin[j] += __shfl_xor(lin[j], 16);
                lin[j] += bg[l * HID + hbase + j];
            }
            if (g == 1 && iq == 0) {
                float4 o = {lin[0], lin[1], lin[2], lin[3]};
                *(float4*)&linT[bl][hl2 * 4] = o;
            }
            __syncthreads();
            if (g == 0 && iq == 0) {
                float4 lt4 = *(const float4*)&linT[bl][hl2 * 4];
                float ltv[4] = {lt4.x, lt4.y, lt4.z, lt4.w};
                float4 sold4 = *(const float4*)(sb_in + (size_t)(b0 + bl) * HID + hbase);
                float sold[4] = {sold4.x, sold4.y, sold4.z, sold4.w};
                float Hv[4], Tv[4], Cv[4];
                if (l == 0) {
                    const float* hp = HTC + ((size_t)(step * BATCH + b0 + bl)) * N3 + hbase;
                    float4 Ht4 = *(const float4*)hp;
                    float4 Tt4 = *(const float4*)(hp + 512);
                    float4 Ct4 = *(const float4*)(hp + 1024);
                    Hv[0]=Ht4.x; Hv[1]=Ht4.y; Hv[2]=Ht4.z; Hv[3]=Ht4.w;
                    Tv[0]=Tt4.x; Tv[1]=Tt4.y; Tv[2]=Tt4.z; Tv[3]=Tt4.w;
                    Cv[0]=Ct4.x; Cv[1]=Ct4.y; Cv[2]=Ct4.z; Cv[3]=Ct4.w;
                }
                float snew[4];
#pragma unroll
                for (int j = 0; j < 4; ++j) {
                    float lh = lin[j], lt = ltv[j];
                    float hv, tv, cv;
                    if (l == 0) {
                        hv = tanhf(Hv[j] + lh);
                        tv = 1.f / (1.f + expf(-(Tv[j] + lt)));
                        cv = 1.f / (1.f + expf(-(Cv[j] + lt)));
                    } else {
                        hv = tanhf(lh);
                        tv = 1.f / (1.f + expf(-lt));
                        cv = tv;
                    }
                    snew[j] = hv * tv + sold[j] * cv;
                }
                float4 o = {snew[0], snew[1], snew[2], snew[3]};
                *(float4*)(s_buf + (cur ^ 1) * (BATCH * HID)
                           + (size_t)(b0 + bl) * HID + hbase) = o;
                if (l == DEPTH - 1) {
                    *(float4*)(out + ((size_t)(step * BATCH + b0 + bl)) * HID + hbase) = o;
                    if (step == S_LEN - 1)
                        *(float4*)(out + (size_t)S_LEN * BATCH * HID
                                   + (size_t)(b0 + bl) * HID + hbase) = o;
                }
            }
            cur ^= 1;
            grid.sync();
        }
    }
}

extern "C" void kernel_launch(void* const* d_in, const int* in_sizes, int n_in,
                              void* d_out, int out_size, void* d_ws, size_t ws_size,
                              hipStream_t stream) {
    const float* inp      = (const float*)d_in[0];
    const float* hidden   = (const float*)d_in[1];
    const float* h_mask   = (const float*)d_in[2];
    const float* s_h_mask = (const float*)d_in[3];
    const float* Wih = (const float*)d_in[4];
    const float* bih = (const float*)d_in[5];
    const float* Wit = (const float*)d_in[6];
    const float* bit_ = (const float*)d_in[7];
    const float* Wic = (const float*)d_in[8];
    const float* bic = (const float*)d_in[9];
    const float* Wh = (const float*)d_in[10];
    const float* bh = (const float*)d_in[11];
    const float* Wt = (const float*)d_in[12];
    const float* bt = (const float*)d_in[13];
    float* out = (float*)d_out;

    float* HTC   = (float*)d_ws;                         // 32768*1536 f32 = 201.3 MB
    float* s_buf = HTC + (size_t)32768 * N3;             // 2*64*512 f32

    // 1) input projections
    dim3 g1(512, 24);
    rhn_inproj<<<g1, 256, 0, stream>>>(inp, h_mask, Wih, Wit, Wic, bih, bit_, bic, HTC);

    // 2) init state s_buf[0] = hidden
    hipMemcpyAsync(s_buf, hidden, (size_t)BATCH * HID * sizeof(float),
                   hipMemcpyDeviceToDevice, stream);

    // 3) recurrence (cooperative: grid.sync per layer-round)
    void* args[] = {(void*)&s_h_mask, (void*)&Wh, (void*)&bh, (void*)&Wt,
                    (void*)&bt, (void*)&HTC, (void*)&s_buf, (void*)&out};
    hipLaunchCooperativeKernel((void*)rhn_scan, dim3(256), dim3(256), args, 0, stream);
}

// Round 2
// 62194.208 us; speedup vs baseline: 1.5401x; 1.5401x over previous
//
#include <hip/hip_runtime.h>
#include <math.h>

#define S_LEN 512
#define BATCH 64
#define IN_DIM 512
#define HID 512
#define DEPTH 5
#define N3 1536  // 3*HID
#define NBLK 256

// =====================================================================
// Input projection GEMM:
//   HTC[m, n] = sum_k (h_mask[m&63, k] * inp[m, k]) * W3[n, k] + b3[n]
//   M = S*B = 32768, N = 1536 (H|T|C), K = 512
// =====================================================================
__global__ __launch_bounds__(256) void rhn_inproj(
    const float* __restrict__ inp, const float* __restrict__ h_mask,
    const float* __restrict__ Wih, const float* __restrict__ Wit,
    const float* __restrict__ Wic, const float* __restrict__ bih,
    const float* __restrict__ bit_, const float* __restrict__ bic,
    float* __restrict__ HTC)
{
    constexpr int BM = 64, BN = 64, BK = 16;
    __shared__ float As[BK][BM + 4];
    __shared__ float Bs[BK][BN + 4];
    const int m0 = blockIdx.x * BM;
    const int n0 = blockIdx.y * BN;
    const int tid = threadIdx.x;
    const int lr = tid >> 2;        // 0..63: row within tile for loads
    const int lk = (tid & 3) * 4;   // 0,4,8,12: k-offset for float4 load
    const int tx = tid & 15, ty = tid >> 4;

    const int n = n0 + lr;
    const float* Wrow = (n < 512) ? (Wih + (size_t)n * 512)
                       : (n < 1024) ? (Wit + (size_t)(n - 512) * 512)
                                    : (Wic + (size_t)(n - 1024) * 512);
    const int m = m0 + lr;
    const float* Arow = inp + (size_t)m * 512;
    const float* Mrow = h_mask + (size_t)(m & 63) * 512;

    float acc[4][4] = {};

    for (int k0 = 0; k0 < 512; k0 += BK) {
        float4 av = *(const float4*)(Arow + k0 + lk);
        float4 mv = *(const float4*)(Mrow + k0 + lk);
        float4 bv = *(const float4*)(Wrow + k0 + lk);
        As[lk + 0][lr] = av.x * mv.x;
        As[lk + 1][lr] = av.y * mv.y;
        As[lk + 2][lr] = av.z * mv.z;
        As[lk + 3][lr] = av.w * mv.w;
        Bs[lk + 0][lr] = bv.x;
        Bs[lk + 1][lr] = bv.y;
        Bs[lk + 2][lr] = bv.z;
        Bs[lk + 3][lr] = bv.w;
        __syncthreads();
#pragma unroll
        for (int kk = 0; kk < BK; ++kk) {
            float4 a = *(const float4*)&As[kk][ty * 4];
            float4 b = *(const float4*)&Bs[kk][tx * 4];
            acc[0][0] += a.x * b.x; acc[0][1] += a.x * b.y; acc[0][2] += a.x * b.z; acc[0][3] += a.x * b.w;
            acc[1][0] += a.y * b.x; acc[1][1] += a.y * b.y; acc[1][2] += a.y * b.z; acc[1][3] += a.y * b.w;
            acc[2][0] += a.z * b.x; acc[2][1] += a.z * b.y; acc[2][2] += a.z * b.z; acc[2][3] += a.z * b.w;
            acc[3][0] += a.w * b.x; acc[3][1] += a.w * b.y; acc[3][2] += a.w * b.z; acc[3][3] += a.w * b.w;
        }
        __syncthreads();
    }

    float bias[4];
#pragma unroll
    for (int j = 0; j < 4; ++j) {
        int nn = n0 + tx * 4 + j;
        bias[j] = (nn < 512) ? bih[nn] : (nn < 1024) ? bit_[nn - 512] : bic[nn - 1024];
    }
#pragma unroll
    for (int i = 0; i < 4; ++i) {
        int mm = m0 + ty * 4 + i;
        float4 o;
        o.x = acc[i][0] + bias[0];
        o.y = acc[i][1] + bias[1];
        o.z = acc[i][2] + bias[2];
        o.w = acc[i][3] + bias[3];
        *(float4*)(HTC + (size_t)mm * N3 + n0 + tx * 4) = o;
    }
}

// ---------------------------------------------------------------------
// Lightweight sense-reversing grid barrier (replaces cg::grid.sync()).
// cnt/gen live in device memory (d_ws), zeroed before launch.
// Release of each block's writes: ACQ_REL fetch_add on cnt.
// Last arriver resets cnt (relaxed) then release-stores gen+1.
// Spinners acquire-load gen (emits L1 invalidate -> fresh global reads).
// ---------------------------------------------------------------------
__device__ __forceinline__ void grid_barrier(unsigned* cnt, unsigned* gen)
{
    __syncthreads();
    if (threadIdx.x == 0) {
        unsigned g = __hip_atomic_load(gen, __ATOMIC_RELAXED, __HIP_MEMORY_SCOPE_AGENT);
        unsigned a = __hip_atomic_fetch_add(cnt, 1u, __ATOMIC_ACQ_REL, __HIP_MEMORY_SCOPE_AGENT);
        if (a == NBLK - 1) {
            __hip_atomic_store(cnt, 0u, __ATOMIC_RELAXED, __HIP_MEMORY_SCOPE_AGENT);
            __hip_atomic_store(gen, g + 1u, __ATOMIC_RELEASE, __HIP_MEMORY_SCOPE_AGENT);
        } else {
            while (__hip_atomic_load(gen, __ATOMIC_ACQUIRE, __HIP_MEMORY_SCOPE_AGENT) == g)
                __builtin_amdgcn_s_sleep(2);
        }
    }
    __syncthreads();
}

// =====================================================================
// Recurrence: persistent kernel, 256 blocks x 256 threads.
// Block = (h-tile of 16) x (b-tile of 8); blockIdx = bi*32 + hi keeps
// all b-tiles of one h-tile on one XCD (weights L2-resident).
// One custom grid barrier per (step, layer) round: 2560 total.
// =====================================================================
__global__ __launch_bounds__(256) void rhn_scan(
    const float* __restrict__ s_h_mask,
    const float* __restrict__ Wh, const float* __restrict__ bh,
    const float* __restrict__ Wt, const float* __restrict__ bt,
    const float* __restrict__ HTC,
    float* __restrict__ s_buf,   // [2][64][512]
    float* __restrict__ out,     // outs [512][64][512] then last [64][512]
    unsigned* __restrict__ bar)  // [0]=cnt, [32]=gen (separate lines)
{
    constexpr int PAD = 4, LW = HID + PAD;  // 516
    __shared__ float mask_s[8][LW];
    __shared__ float sm_s[8][LW];
    __shared__ float linT[8][16];

    unsigned* bcnt = bar;
    unsigned* bgen = bar + 32;

    const int tid = threadIdx.x;
    const int hi = blockIdx.x & 31;
    const int bi = blockIdx.x >> 5;
    const int h0 = hi * 16, b0 = bi * 8;
    const int g   = tid >> 7;
    const int r   = tid & 127;
    const int hl2 = r >> 5;        // 0..3
    const int iq  = (r >> 3) & 3;  // 0..3
    const int bl  = r & 7;
    const int hbase = h0 + hl2 * 4;

    // persistent dropout mask in LDS
    for (int p = tid; p < 1024; p += 256) {
        int b = p >> 7, i4 = p & 127;
        *(float4*)&mask_s[b][i4 * 4] =
            ((const float4*)(s_h_mask + (size_t)(b0 + b) * HID))[i4];
    }

    const float* Wg = g ? Wt : Wh;
    const float* bg = g ? bt : bh;

    int cur = 0;
    for (int step = 0; step < S_LEN; ++step) {
        for (int l = 0; l < DEPTH; ++l) {
            const float* sb_in = s_buf + cur * (BATCH * HID);
            // stage masked state sm = s_h_mask * s into LDS
            for (int p = tid; p < 1024; p += 256) {
                int b = p >> 7, i4 = p & 127;
                float4 v = ((const float4*)(sb_in + (size_t)(b0 + b) * HID))[i4];
                float4 m = *(const float4*)&mask_s[b][i4 * 4];
                v.x *= m.x; v.y *= m.y; v.z *= m.z; v.w *= m.w;
                *(float4*)&sm_s[b][i4 * 4] = v;
            }
            __syncthreads();

            const float* W0 = Wg + ((size_t)l * HID + hbase) * HID;
            const float* W1 = W0 + HID;
            const float* W2 = W0 + 2 * HID;
            const float* W3 = W0 + 3 * HID;
            float4 a0 = {0,0,0,0}, a1 = {0,0,0,0}, a2 = {0,0,0,0}, a3 = {0,0,0,0};
            const float4* smq = (const float4*)&sm_s[bl][0];
#pragma unroll 4
            for (int kk = 0; kk < 32; ++kk) {
                int i4 = iq * 32 + kk;
                float4 sv = smq[i4];
                float4 w0 = ((const float4*)W0)[i4];
                float4 w1 = ((const float4*)W1)[i4];
                float4 w2 = ((const float4*)W2)[i4];
                float4 w3 = ((const float4*)W3)[i4];
                a0.x += w0.x * sv.x; a0.y += w0.y * sv.y; a0.z += w0.z * sv.z; a0.w += w0.w * sv.w;
                a1.x += w1.x * sv.x; a1.y += w1.y * sv.y; a1.z += w1.z * sv.z; a1.w += w1.w * sv.w;
                a2.x += w2.x * sv.x; a2.y += w2.y * sv.y; a2.z += w2.z * sv.z; a2.w += w2.w * sv.w;
                a3.x += w3.x * sv.x; a3.y += w3.y * sv.y; a3.z += w3.z * sv.z; a3.w += w3.w * sv.w;
            }
            float lin[4];
            lin[0] = a0.x + a0.y + a0.z + a0.w;
            lin[1] = a1.x + a1.y + a1.z + a1.w;
            lin[2] = a2.x + a2.y + a2.z + a2.w;
            lin[3] = a3.x + a3.y + a3.z + a3.w;
#pragma unroll
            for (int j = 0; j < 4; ++j) {
                lin[j] += __shfl_xor(lin[j], 8);
                lin[j] += __shfl_xor(lin[j], 16);
                lin[j] += bg[l * HID + hbase + j];
            }
            if (g == 1 && iq == 0) {
                float4 o = {lin[0], lin[1], lin[2], lin[3]};
                *(float4*)&linT[bl][hl2 * 4] = o;
            }
            __syncthreads();
            if (g == 0 && iq == 0) {
                float4 lt4 = *(const float4*)&linT[bl][hl2 * 4];
                float ltv[4] = {lt4.x, lt4.y, lt4.z, lt4.w};
                float4 sold4 = *(const float4*)(sb_in + (size_t)(b0 + bl) * HID + hbase);
                float sold[4] = {sold4.x, sold4.y, sold4.z, sold4.w};
                float Hv[4], Tv[4], Cv[4];
                if (l == 0) {
                    const float* hp = HTC + ((size_t)(step * BATCH + b0 + bl)) * N3 + hbase;
                    float4 Ht4 = *(const float4*)hp;
                    float4 Tt4 = *(const float4*)(hp + 512);
                    float4 Ct4 = *(const float4*)(hp + 1024);
                    Hv[0]=Ht4.x; Hv[1]=Ht4.y; Hv[2]=Ht4.z; Hv[3]=Ht4.w;
                    Tv[0]=Tt4.x; Tv[1]=Tt4.y; Tv[2]=Tt4.z; Tv[3]=Tt4.w;
                    Cv[0]=Ct4.x; Cv[1]=Ct4.y; Cv[2]=Ct4.z; Cv[3]=Ct4.w;
                }
                float snew[4];
#pragma unroll
                for (int j = 0; j < 4; ++j) {
                    float lh = lin[j], lt = ltv[j];
                    float hv, tv, cv;
                    if (l == 0) {
                        hv = tanhf(Hv[j] + lh);
                        tv = 1.f / (1.f + expf(-(Tv[j] + lt)));
                        cv = 1.f / (1.f + expf(-(Cv[j] + lt)));
                    } else {
                        hv = tanhf(lh);
                        tv = 1.f / (1.f + expf(-lt));
                        cv = tv;
                    }
                    snew[j] = hv * tv + sold[j] * cv;
                }
                float4 o = {snew[0], snew[1], snew[2], snew[3]};
                *(float4*)(s_buf + (cur ^ 1) * (BATCH * HID)
                           + (size_t)(b0 + bl) * HID + hbase) = o;
                if (l == DEPTH - 1) {
                    *(float4*)(out + ((size_t)(step * BATCH + b0 + bl)) * HID + hbase) = o;
                    if (step == S_LEN - 1)
                        *(float4*)(out + (size_t)S_LEN * BATCH * HID
                                   + (size_t)(b0 + bl) * HID + hbase) = o;
                }
            }
            cur ^= 1;
            grid_barrier(bcnt, bgen);
        }
    }
}

extern "C" void kernel_launch(void* const* d_in, const int* in_sizes, int n_in,
                              void* d_out, int out_size, void* d_ws, size_t ws_size,
                              hipStream_t stream) {
    const float* inp      = (const float*)d_in[0];
    const float* hidden   = (const float*)d_in[1];
    const float* h_mask   = (const float*)d_in[2];
    const float* s_h_mask = (const float*)d_in[3];
    const float* Wih = (const float*)d_in[4];
    const float* bih = (const float*)d_in[5];
    const float* Wit = (const float*)d_in[6];
    const float* bit_ = (const float*)d_in[7];
    const float* Wic = (const float*)d_in[8];
    const float* bic = (const float*)d_in[9];
    const float* Wh = (const float*)d_in[10];
    const float* bh = (const float*)d_in[11];
    const float* Wt = (const float*)d_in[12];
    const float* bt = (const float*)d_in[13];
    float* out = (float*)d_out;

    float* HTC   = (float*)d_ws;                         // 32768*1536 f32 = 201.3 MB
    float* s_buf = HTC + (size_t)32768 * N3;             // 2*64*512 f32
    unsigned* bar = (unsigned*)(s_buf + 2 * BATCH * HID);

    // zero barrier state (re-poisoned to 0xAA before every timed launch)
    hipMemsetAsync(bar, 0, 64 * sizeof(unsigned), stream);

    // 1) input projections
    dim3 g1(512, 24);
    rhn_inproj<<<g1, 256, 0, stream>>>(inp, h_mask, Wih, Wit, Wic, bih, bit_, bic, HTC);

    // 2) init state s_buf[0] = hidden
    hipMemcpyAsync(s_buf, hidden, (size_t)BATCH * HID * sizeof(float),
                   hipMemcpyDeviceToDevice, stream);

    // 3) recurrence (cooperative launch for co-residency; custom barrier inside)
    void* args[] = {(void*)&s_h_mask, (void*)&Wh, (void*)&bh, (void*)&Wt,
                    (void*)&bt, (void*)&HTC, (void*)&s_buf, (void*)&out,
                    (void*)&bar};
    hipLaunchCooperativeKernel((void*)rhn_scan, dim3(NBLK), dim3(256), args, 0, stream);
}

// Round 3
// 23646.928 us; speedup vs baseline: 4.0506x; 2.6301x over previous
//
#include <hip/hip_runtime.h>
#include <math.h>

#define S_LEN 512
#define BATCH 64
#define IN_DIM 512
#define HID 512
#define DEPTH 5
#define N3 1536  // 3*HID
#define NBLK 256

// =====================================================================
// Input projection GEMM (128x128 tile, 8x8 microtile):
//   HTC[m, n] = sum_k (h_mask[m&63, k] * inp[m, k]) * W3[n, k] + b3[n]
//   M = S*B = 32768, N = 1536 (H|T|C), K = 512
// =====================================================================
__global__ __launch_bounds__(256) void rhn_inproj(
    const float* __restrict__ inp, const float* __restrict__ h_mask,
    const float* __restrict__ Wih, const float* __restrict__ Wit,
    const float* __restrict__ Wic, const float* __restrict__ bih,
    const float* __restrict__ bit_, const float* __restrict__ bic,
    float* __restrict__ HTC)
{
    constexpr int BM = 128, BN = 128, BK = 16, LW = BM + 4;
    __shared__ float As[BK][LW];   // [k][m]
    __shared__ float Bs[BK][LW];   // [k][n]
    const int m0 = blockIdx.x * BM;
    const int n0 = blockIdx.y * BN;
    const int tid = threadIdx.x;
    const int lrow = tid & 127;     // row within tile for staging
    const int lkq  = tid >> 7;      // 0..1
    const int tx = tid & 15, ty = tid >> 4;   // 16x16 threads -> 8x8 micro

    const float* Arow = inp + (size_t)(m0 + lrow) * 512;
    const float* Mrow = h_mask + (size_t)((m0 + lrow) & 63) * 512;
    const int n = n0 + lrow;
    const float* Wrow = (n < 512) ? (Wih + (size_t)n * 512)
                       : (n < 1024) ? (Wit + (size_t)(n - 512) * 512)
                                    : (Wic + (size_t)(n - 1024) * 512);

    float acc[8][8] = {};

    for (int k0 = 0; k0 < 512; k0 += BK) {
#pragma unroll
        for (int it = 0; it < 2; ++it) {
            int kq = lkq * 2 + it;   // 0..3 float4 within BK
            float4 av = *(const float4*)(Arow + k0 + kq * 4);
            float4 mv = *(const float4*)(Mrow + k0 + kq * 4);
            float4 bv = *(const float4*)(Wrow + k0 + kq * 4);
            As[kq * 4 + 0][lrow] = av.x * mv.x;
            As[kq * 4 + 1][lrow] = av.y * mv.y;
            As[kq * 4 + 2][lrow] = av.z * mv.z;
            As[kq * 4 + 3][lrow] = av.w * mv.w;
            Bs[kq * 4 + 0][lrow] = bv.x;
            Bs[kq * 4 + 1][lrow] = bv.y;
            Bs[kq * 4 + 2][lrow] = bv.z;
            Bs[kq * 4 + 3][lrow] = bv.w;
        }
        __syncthreads();
#pragma unroll
        for (int kk = 0; kk < BK; ++kk) {
            float4 a0 = *(const float4*)&As[kk][ty * 8];
            float4 a1 = *(const float4*)&As[kk][ty * 8 + 4];
            float4 bv0 = *(const float4*)&Bs[kk][tx * 8];
            float4 bv1 = *(const float4*)&Bs[kk][tx * 8 + 4];
            float am[8] = {a0.x, a0.y, a0.z, a0.w, a1.x, a1.y, a1.z, a1.w};
            float bn[8] = {bv0.x, bv0.y, bv0.z, bv0.w, bv1.x, bv1.y, bv1.z, bv1.w};
#pragma unroll
            for (int i = 0; i < 8; ++i)
#pragma unroll
                for (int j = 0; j < 8; ++j)
                    acc[i][j] += am[i] * bn[j];
        }
        __syncthreads();
    }

    float bias[8];
#pragma unroll
    for (int j = 0; j < 8; ++j) {
        int nn = n0 + tx * 8 + j;
        bias[j] = (nn < 512) ? bih[nn] : (nn < 1024) ? bit_[nn - 512] : bic[nn - 1024];
    }
#pragma unroll
    for (int i = 0; i < 8; ++i) {
        int mm = m0 + ty * 8 + i;
        float4 o0, o1;
        o0.x = acc[i][0] + bias[0]; o0.y = acc[i][1] + bias[1];
        o0.z = acc[i][2] + bias[2]; o0.w = acc[i][3] + bias[3];
        o1.x = acc[i][4] + bias[4]; o1.y = acc[i][5] + bias[5];
        o1.z = acc[i][6] + bias[6]; o1.w = acc[i][7] + bias[7];
        *(float4*)(HTC + (size_t)mm * N3 + n0 + tx * 8)     = o0;
        *(float4*)(HTC + (size_t)mm * N3 + n0 + tx * 8 + 4) = o1;
    }
}

// ---------------------------------------------------------------------
// Fence-free grid barrier: relaxed agent-scope atomics only (no wbl2 /
// buffer_inv whole-cache ops). Monotonic counters -> no reset races.
// Cross-block DATA (s_buf) is accessed exclusively with relaxed
// agent-scope atomics (coherent point), so no acquire/release needed.
// bar[0]=root ctr, bar[32]=generation, bar[64+g*32]=group ctr (16 groups).
// ---------------------------------------------------------------------
__device__ __forceinline__ void grid_barrier(unsigned* bar, unsigned round)
{
    // drain this wave's vmcnt so s_buf stores are at the coherence point
    asm volatile("s_waitcnt vmcnt(0)" ::: "memory");
    __syncthreads();   // all waves drained (compiler adds waitcnt per wave)
    if (threadIdx.x == 0) {
        unsigned g16 = blockIdx.x >> 4;
        unsigned* gcnt = bar + 64 + g16 * 32;
        unsigned a = __hip_atomic_fetch_add(gcnt, 1u, __ATOMIC_RELAXED,
                                            __HIP_MEMORY_SCOPE_AGENT);
        if (a == round * 16u + 15u) {
            unsigned b = __hip_atomic_fetch_add(bar, 1u, __ATOMIC_RELAXED,
                                                __HIP_MEMORY_SCOPE_AGENT);
            if (b == round * 16u + 15u) {
                __hip_atomic_store(bar + 32, round + 1u, __ATOMIC_RELAXED,
                                   __HIP_MEMORY_SCOPE_AGENT);
            }
        }
        while (__hip_atomic_load(bar + 32, __ATOMIC_RELAXED,
                                 __HIP_MEMORY_SCOPE_AGENT) < round + 1u)
            __builtin_amdgcn_s_sleep(1);
        asm volatile("" ::: "memory");
    }
    __syncthreads();
}

// =====================================================================
// Recurrence: persistent kernel, 256 blocks x 256 threads.
// Block = (h-tile of 16) x (b-tile of 8); blockIdx = bi*32 + hi.
// s_buf accessed only via relaxed agent atomics (cross-XCD coherent).
// Weights/HTC/mask: ordinary cached loads (read-only, stay L2-resident).
// =====================================================================
__global__ __launch_bounds__(256) void rhn_scan(
    const float* __restrict__ s_h_mask,
    const float* __restrict__ Wh, const float* __restrict__ bh,
    const float* __restrict__ Wt, const float* __restrict__ bt,
    const float* __restrict__ HTC,
    float* __restrict__ s_buf,   // [2][64][512]
    float* __restrict__ out,     // outs [512][64][512] then last [64][512]
    unsigned* __restrict__ bar)
{
    constexpr int PAD = 4, LW = HID + PAD;  // 516
    __shared__ float mask_s[8][LW];
    __shared__ float sm_s[8][LW];
    __shared__ float linT[8][16];

    const int tid = threadIdx.x;
    const int hi = blockIdx.x & 31;
    const int bi = blockIdx.x >> 5;
    const int h0 = hi * 16, b0 = bi * 8;
    const int g   = tid >> 7;
    const int r   = tid & 127;
    const int hl2 = r >> 5;        // 0..3
    const int iq  = (r >> 3) & 3;  // 0..3
    const int bl  = r & 7;
    const int hbase = h0 + hl2 * 4;

    // persistent dropout mask in LDS (read-only input: ordinary loads)
    for (int p = tid; p < 1024; p += 256) {
        int b = p >> 7, i4 = p & 127;
        *(float4*)&mask_s[b][i4 * 4] =
            ((const float4*)(s_h_mask + (size_t)(b0 + b) * HID))[i4];
    }

    const float* Wg = g ? Wt : Wh;
    const float* bg = g ? bt : bh;

    int cur = 0;
    unsigned round = 0;
    for (int step = 0; step < S_LEN; ++step) {
        for (int l = 0; l < DEPTH; ++l) {
            const float* sb_in = s_buf + cur * (BATCH * HID);
            // stage masked state sm = s_h_mask * s into LDS
            // (coherent relaxed atomic loads: bypass stale L1/L2)
            for (int p = tid; p < 1024; p += 256) {
                int b = p >> 7, i4 = p & 127;
                const float* src = sb_in + (size_t)(b0 + b) * HID + i4 * 4;
                float4 v;
                v.x = __hip_atomic_load(src + 0, __ATOMIC_RELAXED, __HIP_MEMORY_SCOPE_AGENT);
                v.y = __hip_atomic_load(src + 1, __ATOMIC_RELAXED, __HIP_MEMORY_SCOPE_AGENT);
                v.z = __hip_atomic_load(src + 2, __ATOMIC_RELAXED, __HIP_MEMORY_SCOPE_AGENT);
                v.w = __hip_atomic_load(src + 3, __ATOMIC_RELAXED, __HIP_MEMORY_SCOPE_AGENT);
                float4 m = *(const float4*)&mask_s[b][i4 * 4];
                v.x *= m.x; v.y *= m.y; v.z *= m.z; v.w *= m.w;
                *(float4*)&sm_s[b][i4 * 4] = v;
            }
            __syncthreads();

            const float* W0 = Wg + ((size_t)l * HID + hbase) * HID;
            const float* W1 = W0 + HID;
            const float* W2 = W0 + 2 * HID;
            const float* W3 = W0 + 3 * HID;
            float4 a0 = {0,0,0,0}, a1 = {0,0,0,0}, a2 = {0,0,0,0}, a3 = {0,0,0,0};
            const float4* smq = (const float4*)&sm_s[bl][0];
#pragma unroll 4
            for (int kk = 0; kk < 32; ++kk) {
                int i4 = iq * 32 + kk;
                float4 sv = smq[i4];
                float4 w0 = ((const float4*)W0)[i4];
                float4 w1 = ((const float4*)W1)[i4];
                float4 w2 = ((const float4*)W2)[i4];
                float4 w3 = ((const float4*)W3)[i4];
                a0.x += w0.x * sv.x; a0.y += w0.y * sv.y; a0.z += w0.z * sv.z; a0.w += w0.w * sv.w;
                a1.x += w1.x * sv.x; a1.y += w1.y * sv.y; a1.z += w1.z * sv.z; a1.w += w1.w * sv.w;
                a2.x += w2.x * sv.x; a2.y += w2.y * sv.y; a2.z += w2.z * sv.z; a2.w += w2.w * sv.w;
                a3.x += w3.x * sv.x; a3.y += w3.y * sv.y; a3.z += w3.z * sv.z; a3.w += w3.w * sv.w;
            }
            float lin[4];
            lin[0] = a0.x + a0.y + a0.z + a0.w;
            lin[1] = a1.x + a1.y + a1.z + a1.w;
            lin[2] = a2.x + a2.y + a2.z + a2.w;
            lin[3] = a3.x + a3.y + a3.z + a3.w;
#pragma unroll
            for (int j = 0; j < 4; ++j) {
                lin[j] += __shfl_xor(lin[j], 8);
                lin[j] += __shfl_xor(lin[j], 16);
                lin[j] += bg[l * HID + hbase + j];
            }
            if (g == 1 && iq == 0) {
                float4 o = {lin[0], lin[1], lin[2], lin[3]};
                *(float4*)&linT[bl][hl2 * 4] = o;
            }
            __syncthreads();
            if (g == 0 && iq == 0) {
                float4 lt4 = *(const float4*)&linT[bl][hl2 * 4];
                float ltv[4] = {lt4.x, lt4.y, lt4.z, lt4.w};
                const float* sp = sb_in + (size_t)(b0 + bl) * HID + hbase;
                float sold[4];
#pragma unroll
                for (int j = 0; j < 4; ++j)
                    sold[j] = __hip_atomic_load(sp + j, __ATOMIC_RELAXED, __HIP_MEMORY_SCOPE_AGENT);
                float Hv[4], Tv[4], Cv[4];
                if (l == 0) {
                    const float* hp = HTC + ((size_t)(step * BATCH + b0 + bl)) * N3 + hbase;
                    float4 Ht4 = *(const float4*)hp;
                    float4 Tt4 = *(const float4*)(hp + 512);
                    float4 Ct4 = *(const float4*)(hp + 1024);
                    Hv[0]=Ht4.x; Hv[1]=Ht4.y; Hv[2]=Ht4.z; Hv[3]=Ht4.w;
                    Tv[0]=Tt4.x; Tv[1]=Tt4.y; Tv[2]=Tt4.z; Tv[3]=Tt4.w;
                    Cv[0]=Ct4.x; Cv[1]=Ct4.y; Cv[2]=Ct4.z; Cv[3]=Ct4.w;
                }
                float snew[4];
#pragma unroll
                for (int j = 0; j < 4; ++j) {
                    float lh = lin[j], lt = ltv[j];
                    float hv, tv, cv;
                    if (l == 0) {
                        hv = tanhf(Hv[j] + lh);
                        tv = 1.f / (1.f + expf(-(Tv[j] + lt)));
                        cv = 1.f / (1.f + expf(-(Cv[j] + lt)));
                    } else {
                        hv = tanhf(lh);
                        tv = 1.f / (1.f + expf(-lt));
                        cv = tv;
                    }
                    snew[j] = hv * tv + sold[j] * cv;
                }
                float* dp = s_buf + (cur ^ 1) * (BATCH * HID)
                            + (size_t)(b0 + bl) * HID + hbase;
#pragma unroll
                for (int j = 0; j < 4; ++j)
                    __hip_atomic_store(dp + j, snew[j], __ATOMIC_RELAXED, __HIP_MEMORY_SCOPE_AGENT);
                if (l == DEPTH - 1) {
                    float4 o = {snew[0], snew[1], snew[2], snew[3]};
                    *(float4*)(out + ((size_t)(step * BATCH + b0 + bl)) * HID + hbase) = o;
                    if (step == S_LEN - 1)
                        *(float4*)(out + (size_t)S_LEN * BATCH * HID
                                   + (size_t)(b0 + bl) * HID + hbase) = o;
                }
            }
            cur ^= 1;
            grid_barrier(bar, round);
            ++round;
        }
    }
}

extern "C" void kernel_launch(void* const* d_in, const int* in_sizes, int n_in,
                              void* d_out, int out_size, void* d_ws, size_t ws_size,
                              hipStream_t stream) {
    const float* inp      = (const float*)d_in[0];
    const float* hidden   = (const float*)d_in[1];
    const float* h_mask   = (const float*)d_in[2];
    const float* s_h_mask = (const float*)d_in[3];
    const float* Wih = (const float*)d_in[4];
    const float* bih = (const float*)d_in[5];
    const float* Wit = (const float*)d_in[6];
    const float* bit_ = (const float*)d_in[7];
    const float* Wic = (const float*)d_in[8];
    const float* bic = (const float*)d_in[9];
    const float* Wh = (const float*)d_in[10];
    const float* bh = (const float*)d_in[11];
    const float* Wt = (const float*)d_in[12];
    const float* bt = (const float*)d_in[13];
    float* out = (float*)d_out;

    float* HTC   = (float*)d_ws;                         // 32768*1536 f32 = 201.3 MB
    float* s_buf = HTC + (size_t)32768 * N3;             // 2*64*512 f32
    unsigned* bar = (unsigned*)(s_buf + 2 * BATCH * HID);

    // zero barrier state (root + gen + 16 group counters)
    hipMemsetAsync(bar, 0, (64 + 16 * 32) * sizeof(unsigned), stream);

    // 1) input projections
    dim3 g1(256, 12);
    rhn_inproj<<<g1, 256, 0, stream>>>(inp, h_mask, Wih, Wit, Wic, bih, bit_, bic, HTC);

    // 2) init state s_buf[0] = hidden
    hipMemcpyAsync(s_buf, hidden, (size_t)BATCH * HID * sizeof(float),
                   hipMemcpyDeviceToDevice, stream);

    // 3) recurrence (cooperative launch for co-residency; fence-free barrier)
    void* args[] = {(void*)&s_h_mask, (void*)&Wh, (void*)&bh, (void*)&Wt,
                    (void*)&bt, (void*)&HTC, (void*)&s_buf, (void*)&out,
                    (void*)&bar};
    hipLaunchCooperativeKernel((void*)rhn_scan, dim3(NBLK), dim3(256), args, 0, stream);
}

// Round 5
// 17758.701 us; speedup vs baseline: 5.3937x; 1.3316x over previous
//
#include <hip/hip_runtime.h>
#include <math.h>

#define S_LEN 512
#define BATCH 64
#define IN_DIM 512
#define HID 512
#define DEPTH 5
#define N3 1536  // 3*HID
#define NBLK 256

// native 4xfloat vector: usable directly in asm "v" constraints (4 VGPRs)
typedef float floatx4 __attribute__((ext_vector_type(4)));

// coherent (agent-scope / cross-XCD) 16B store. sc1 = agent scope on gfx950.
#define STOREC(ptr, val) \
    asm volatile("global_store_dwordx4 %0, %1, off sc1" :: "v"(ptr), "v"(val) : "memory")

// =====================================================================
// Input projection GEMM (128x128 tile, 8x8 microtile):
//   HTC[m, n] = sum_k (h_mask[m&63, k] * inp[m, k]) * W3[n, k] + b3[n]
// =====================================================================
__global__ __launch_bounds__(256) void rhn_inproj(
    const float* __restrict__ inp, const float* __restrict__ h_mask,
    const float* __restrict__ Wih, const float* __restrict__ Wit,
    const float* __restrict__ Wic, const float* __restrict__ bih,
    const float* __restrict__ bit_, const float* __restrict__ bic,
    float* __restrict__ HTC)
{
    constexpr int BM = 128, BN = 128, BK = 16, LW = BM + 4;
    __shared__ float As[BK][LW];
    __shared__ float Bs[BK][LW];
    const int m0 = blockIdx.x * BM;
    const int n0 = blockIdx.y * BN;
    const int tid = threadIdx.x;
    const int lrow = tid & 127;
    const int lkq  = tid >> 7;
    const int tx = tid & 15, ty = tid >> 4;

    const float* Arow = inp + (size_t)(m0 + lrow) * 512;
    const float* Mrow = h_mask + (size_t)((m0 + lrow) & 63) * 512;
    const int n = n0 + lrow;
    const float* Wrow = (n < 512) ? (Wih + (size_t)n * 512)
                       : (n < 1024) ? (Wit + (size_t)(n - 512) * 512)
                                    : (Wic + (size_t)(n - 1024) * 512);

    float acc[8][8] = {};

    for (int k0 = 0; k0 < 512; k0 += BK) {
#pragma unroll
        for (int it = 0; it < 2; ++it) {
            int kq = lkq * 2 + it;
            float4 av = *(const float4*)(Arow + k0 + kq * 4);
            float4 mv = *(const float4*)(Mrow + k0 + kq * 4);
            float4 bv = *(const float4*)(Wrow + k0 + kq * 4);
            As[kq * 4 + 0][lrow] = av.x * mv.x;
            As[kq * 4 + 1][lrow] = av.y * mv.y;
            As[kq * 4 + 2][lrow] = av.z * mv.z;
            As[kq * 4 + 3][lrow] = av.w * mv.w;
            Bs[kq * 4 + 0][lrow] = bv.x;
            Bs[kq * 4 + 1][lrow] = bv.y;
            Bs[kq * 4 + 2][lrow] = bv.z;
            Bs[kq * 4 + 3][lrow] = bv.w;
        }
        __syncthreads();
#pragma unroll
        for (int kk = 0; kk < BK; ++kk) {
            float4 a0 = *(const float4*)&As[kk][ty * 8];
            float4 a1 = *(const float4*)&As[kk][ty * 8 + 4];
            float4 bv0 = *(const float4*)&Bs[kk][tx * 8];
            float4 bv1 = *(const float4*)&Bs[kk][tx * 8 + 4];
            float am[8] = {a0.x, a0.y, a0.z, a0.w, a1.x, a1.y, a1.z, a1.w};
            float bn[8] = {bv0.x, bv0.y, bv0.z, bv0.w, bv1.x, bv1.y, bv1.z, bv1.w};
#pragma unroll
            for (int i = 0; i < 8; ++i)
#pragma unroll
                for (int j = 0; j < 8; ++j)
                    acc[i][j] += am[i] * bn[j];
        }
        __syncthreads();
    }

    float bias[8];
#pragma unroll
    for (int j = 0; j < 8; ++j) {
        int nn = n0 + tx * 8 + j;
        bias[j] = (nn < 512) ? bih[nn] : (nn < 1024) ? bit_[nn - 512] : bic[nn - 1024];
    }
#pragma unroll
    for (int i = 0; i < 8; ++i) {
        int mm = m0 + ty * 8 + i;
        float4 o0, o1;
        o0.x = acc[i][0] + bias[0]; o0.y = acc[i][1] + bias[1];
        o0.z = acc[i][2] + bias[2]; o0.w = acc[i][3] + bias[3];
        o1.x = acc[i][4] + bias[4]; o1.y = acc[i][5] + bias[5];
        o1.z = acc[i][6] + bias[6]; o1.w = acc[i][7] + bias[7];
        *(float4*)(HTC + (size_t)mm * N3 + n0 + tx * 8)     = o0;
        *(float4*)(HTC + (size_t)mm * N3 + n0 + tx * 8 + 4) = o1;
    }
}

__device__ __forceinline__ float fast_sig(float x) {
    return __builtin_amdgcn_rcpf(1.f + __expf(-x));
}
__device__ __forceinline__ float fast_tanh(float x) {
    return 2.f * fast_sig(2.f * x) - 1.f;
}

// =====================================================================
// Recurrence: persistent kernel, 256 blocks x 256 threads.
// Block = (h-tile 16) x (b-tile 8). 8 independent barrier groups (by bi):
// only the 32 blocks sharing a b-tile exchange state; each group has its
// own single-level monotonic barrier (1 RMW + 1 store + poll).
// State slice owned by a thread lives in registers across all rounds.
// All cross-block s_buf traffic = sc1 dwordx4 (coherent, vectorized).
// =====================================================================
__global__ __launch_bounds__(256) void rhn_scan(
    const float* __restrict__ hidden,
    const float* __restrict__ s_h_mask,
    const float* __restrict__ Wh, const float* __restrict__ bh,
    const float* __restrict__ Wt, const float* __restrict__ bt,
    const float* __restrict__ HTC,
    float* __restrict__ s_buf,   // [2][64][512]
    float* __restrict__ out,     // outs [512][64][512] then last [64][512]
    unsigned* __restrict__ bar)  // gen[bi] @ bi*32, cnt[bi] @ 256+bi*32
{
    constexpr int PAD = 4, LW = HID + PAD;  // 516
    __shared__ float mask_s[8][LW];
    __shared__ float sm_s[8][LW];
    __shared__ float linT[8][16];

    const int tid = threadIdx.x;
    const int hi = blockIdx.x & 31;
    const int bi = blockIdx.x >> 5;
    const int h0 = hi * 16, b0 = bi * 8;
    const int g   = tid >> 7;
    const int r   = tid & 127;
    const int hl2 = r >> 5;
    const int iq  = (r >> 3) & 3;
    const int bl  = r & 7;
    const int hbase = h0 + hl2 * 4;

    unsigned* ggen = bar + (size_t)bi * 32;
    unsigned* gcnt = bar + 256 + (size_t)bi * 32;

    // stage-slot mapping shared by mask init and per-round staging
    const int p0 = tid,       b_0 = p0 >> 7, i40 = p0 & 127;
    const int p1 = tid + 256, b_1 = p1 >> 7, i41 = p1 & 127;
    const int p2 = tid + 512, b_2 = p2 >> 7, i42 = p2 & 127;
    const int p3 = tid + 768, b_3 = p3 >> 7, i43 = p3 & 127;

    // persistent dropout mask in LDS (read-only input: plain loads)
    *(float4*)&mask_s[b_0][i40 * 4] = ((const float4*)(s_h_mask + (size_t)(b0 + b_0) * HID))[i40];
    *(float4*)&mask_s[b_1][i41 * 4] = ((const float4*)(s_h_mask + (size_t)(b0 + b_1) * HID))[i41];
    *(float4*)&mask_s[b_2][i42 * 4] = ((const float4*)(s_h_mask + (size_t)(b0 + b_2) * HID))[i42];
    *(float4*)&mask_s[b_3][i43 * 4] = ((const float4*)(s_h_mask + (size_t)(b0 + b_3) * HID))[i43];

    const float* Wg = g ? Wt : Wh;
    const float* bg = g ? bt : bh;
    const bool tail = (g == 0 && iq == 0);

    // register-resident state slice + HTC prefetch (tail threads only)
    floatx4 s_reg = {0, 0, 0, 0};
    float4 Hp = {0,0,0,0}, Tp = {0,0,0,0}, Cp = {0,0,0,0};
    if (tail) {
        float4 s0 = *(const float4*)(hidden + (size_t)(b0 + bl) * HID + hbase);
        s_reg.x = s0.x; s_reg.y = s0.y; s_reg.z = s0.z; s_reg.w = s0.w;
        const float* hp = HTC + (size_t)(b0 + bl) * N3 + hbase;  // step 0
        Hp = *(const float4*)hp;
        Tp = *(const float4*)(hp + 512);
        Cp = *(const float4*)(hp + 1024);
    }

    const float* sp0 = s_buf + (size_t)(b0 + b_0) * HID + i40 * 4;
    const float* sp1 = s_buf + (size_t)(b0 + b_1) * HID + i41 * 4;
    const float* sp2 = s_buf + (size_t)(b0 + b_2) * HID + i42 * 4;
    const float* sp3 = s_buf + (size_t)(b0 + b_3) * HID + i43 * 4;

    int cur = 0;
    unsigned round = 0;
    bool pend_out = false;
    floatx4 pend_val = {0,0,0,0};

    for (int step = 0; step < S_LEN; ++step) {
        for (int l = 0; l < DEPTH; ++l) {
            const size_t coff = (size_t)cur * (BATCH * HID);

            // retire pending out-write from previous round (fire-and-forget)
            if (pend_out) {
                *(float4*)(out + ((size_t)((step - (l == 0)) * BATCH + b0 + bl)) * HID + hbase)
                    = *(float4*)&pend_val;
                pend_out = false;
            }

            // ---- stage masked state into LDS: 4 coherent vector loads
            //      issued back-to-back, drained by ONE waitcnt (same asm) ----
            floatx4 sv0, sv1, sv2, sv3;
            asm volatile(
                "global_load_dwordx4 %0, %4, off sc1\n\t"
                "global_load_dwordx4 %1, %5, off sc1\n\t"
                "global_load_dwordx4 %2, %6, off sc1\n\t"
                "global_load_dwordx4 %3, %7, off sc1\n\t"
                "s_waitcnt vmcnt(0)"
                : "=&v"(sv0), "=&v"(sv1), "=&v"(sv2), "=&v"(sv3)
                : "v"(sp0 + coff), "v"(sp1 + coff), "v"(sp2 + coff), "v"(sp3 + coff)
                : "memory");
            {
                floatx4 m;
                m = *(const floatx4*)&mask_s[b_0][i40 * 4];
                *(floatx4*)&sm_s[b_0][i40 * 4] = sv0 * m;
                m = *(const floatx4*)&mask_s[b_1][i41 * 4];
                *(floatx4*)&sm_s[b_1][i41 * 4] = sv1 * m;
                m = *(const floatx4*)&mask_s[b_2][i42 * 4];
                *(floatx4*)&sm_s[b_2][i42 * 4] = sv2 * m;
                m = *(const floatx4*)&mask_s[b_3][i43 * 4];
                *(floatx4*)&sm_s[b_3][i43 * 4] = sv3 * m;
            }
            __syncthreads();

            // ---- dot: 4 W rows x 128-elem i-quarter per thread ----
            const float* W0 = Wg + ((size_t)l * HID + hbase) * HID;
            const float* W1 = W0 + HID;
            const float* W2 = W0 + 2 * HID;
            const float* W3 = W0 + 3 * HID;
            float4 a0 = {0,0,0,0}, a1 = {0,0,0,0}, a2 = {0,0,0,0}, a3 = {0,0,0,0};
            const float4* smq = (const float4*)&sm_s[bl][0];
#pragma unroll 4
            for (int kk = 0; kk < 32; ++kk) {
                int i4 = iq * 32 + kk;
                float4 sv = smq[i4];
                float4 w0 = ((const float4*)W0)[i4];
                float4 w1 = ((const float4*)W1)[i4];
                float4 w2 = ((const float4*)W2)[i4];
                float4 w3 = ((const float4*)W3)[i4];
                a0.x += w0.x * sv.x; a0.y += w0.y * sv.y; a0.z += w0.z * sv.z; a0.w += w0.w * sv.w;
                a1.x += w1.x * sv.x; a1.y += w1.y * sv.y; a1.z += w1.z * sv.z; a1.w += w1.w * sv.w;
                a2.x += w2.x * sv.x; a2.y += w2.y * sv.y; a2.z += w2.z * sv.z; a2.w += w2.w * sv.w;
                a3.x += w3.x * sv.x; a3.y += w3.y * sv.y; a3.z += w3.z * sv.z; a3.w += w3.w * sv.w;
            }
            float lin[4];
            lin[0] = a0.x + a0.y + a0.z + a0.w;
            lin[1] = a1.x + a1.y + a1.z + a1.w;
            lin[2] = a2.x + a2.y + a2.z + a2.w;
            lin[3] = a3.x + a3.y + a3.z + a3.w;
#pragma unroll
            for (int j = 0; j < 4; ++j) {
                lin[j] += __shfl_xor(lin[j], 8);
                lin[j] += __shfl_xor(lin[j], 16);
                lin[j] += bg[l * HID + hbase + j];
            }
            if (g == 1 && iq == 0) {
                float4 o = {lin[0], lin[1], lin[2], lin[3]};
                *(float4*)&linT[bl][hl2 * 4] = o;
            }
            __syncthreads();

            // ---- tail: gates + state update (32 threads/block) ----
            if (tail) {
                float4 lt4 = *(const float4*)&linT[bl][hl2 * 4];
                float ltv[4] = {lt4.x, lt4.y, lt4.z, lt4.w};
                float sold[4] = {s_reg.x, s_reg.y, s_reg.z, s_reg.w};
                float Hv[4] = {Hp.x, Hp.y, Hp.z, Hp.w};
                float Tv[4] = {Tp.x, Tp.y, Tp.z, Tp.w};
                float Cv[4] = {Cp.x, Cp.y, Cp.z, Cp.w};
                float snew[4];
#pragma unroll
                for (int j = 0; j < 4; ++j) {
                    float lh = lin[j], lt = ltv[j];
                    float hv, tv, cv;
                    if (l == 0) {
                        hv = fast_tanh(Hv[j] + lh);
                        tv = fast_sig(Tv[j] + lt);
                        cv = fast_sig(Cv[j] + lt);
                    } else {
                        hv = fast_tanh(lh);
                        tv = fast_sig(lt);
                        cv = tv;
                    }
                    snew[j] = hv * tv + sold[j] * cv;
                }
                s_reg.x = snew[0]; s_reg.y = snew[1];
                s_reg.z = snew[2]; s_reg.w = snew[3];
                float* dp = s_buf + ((size_t)(cur ^ 1)) * (BATCH * HID)
                            + (size_t)(b0 + bl) * HID + hbase;
                STOREC(dp, s_reg);
                // prefetch next step's HTC right after consuming this step's
                if (l == 0 && step + 1 < S_LEN) {
                    const float* hp = HTC + ((size_t)((step + 1) * BATCH + b0 + bl)) * N3 + hbase;
                    Hp = *(const float4*)hp;
                    Tp = *(const float4*)(hp + 512);
                    Cp = *(const float4*)(hp + 1024);
                }
                if (l == DEPTH - 1) {
                    pend_out = true;   // retire next round
                    pend_val = s_reg;
                }
            }
            cur ^= 1;

            // ---- per-group barrier (32 arrivals, single level) ----
            asm volatile("s_waitcnt vmcnt(0)" ::: "memory");
            __syncthreads();
            if (tid == 0) {
                unsigned a = __hip_atomic_fetch_add(gcnt, 1u, __ATOMIC_RELAXED,
                                                    __HIP_MEMORY_SCOPE_AGENT);
                if (a == round * 32u + 31u) {
                    __hip_atomic_store(ggen, round + 1u, __ATOMIC_RELAXED,
                                       __HIP_MEMORY_SCOPE_AGENT);
                } else {
                    while (__hip_atomic_load(ggen, __ATOMIC_RELAXED,
                                             __HIP_MEMORY_SCOPE_AGENT) < round + 1u)
                        __builtin_amdgcn_s_sleep(1);
                }
            }
            __syncthreads();
            ++round;
        }
    }

    // final out rows: outs[last step] + last
    if (tail) {
        *(float4*)(out + ((size_t)((S_LEN - 1) * BATCH + b0 + bl)) * HID + hbase)
            = *(float4*)&pend_val;
        *(float4*)(out + (size_t)S_LEN * BATCH * HID + (size_t)(b0 + bl) * HID + hbase)
            = *(float4*)&pend_val;
    }
}

extern "C" void kernel_launch(void* const* d_in, const int* in_sizes, int n_in,
                              void* d_out, int out_size, void* d_ws, size_t ws_size,
                              hipStream_t stream) {
    const float* inp      = (const float*)d_in[0];
    const float* hidden   = (const float*)d_in[1];
    const float* h_mask   = (const float*)d_in[2];
    const float* s_h_mask = (const float*)d_in[3];
    const float* Wih = (const float*)d_in[4];
    const float* bih = (const float*)d_in[5];
    const float* Wit = (const float*)d_in[6];
    const float* bit_ = (const float*)d_in[7];
    const float* Wic = (const float*)d_in[8];
    const float* bic = (const float*)d_in[9];
    const float* Wh = (const float*)d_in[10];
    const float* bh = (const float*)d_in[11];
    const float* Wt = (const float*)d_in[12];
    const float* bt = (const float*)d_in[13];
    float* out = (float*)d_out;

    float* HTC   = (float*)d_ws;                         // 32768*1536 f32 = 201.3 MB
    float* s_buf = HTC + (size_t)32768 * N3;             // 2*64*512 f32
    unsigned* bar = (unsigned*)(s_buf + 2 * BATCH * HID);

    // zero barrier state: gen[8] @ [0..255], cnt[8] @ [256..511]
    (void)hipMemsetAsync(bar, 0, 512 * sizeof(unsigned), stream);

    // 1) input projections
    dim3 g1(256, 12);
    rhn_inproj<<<g1, 256, 0, stream>>>(inp, h_mask, Wih, Wit, Wic, bih, bit_, bic, HTC);

    // 2) init state s_buf[0] = hidden
    (void)hipMemcpyAsync(s_buf, hidden, (size_t)BATCH * HID * sizeof(float),
                         hipMemcpyDeviceToDevice, stream);

    // 3) recurrence
    void* args[] = {(void*)&hidden, (void*)&s_h_mask, (void*)&Wh, (void*)&bh,
                    (void*)&Wt, (void*)&bt, (void*)&HTC, (void*)&s_buf,
                    (void*)&out, (void*)&bar};
    (void)hipLaunchCooperativeKernel((void*)rhn_scan, dim3(NBLK), dim3(256), args, 0, stream);
}